// Round 3
// baseline (129.193 us; speedup 1.0000x reference)
//
#include <hip/hip_runtime.h>
#include <hip/hip_bf16.h>

#define DIM   1024
#define HEADS 16
#define B     2
#define N     2048
#define ROWS  16   // output rows per block in outer kernel

typedef float f32x4 __attribute__((ext_vector_type(4)));

// ---------------------------------------------------------------------------
// Kernel 1: logits[b,h,n] = dot(x[b,n,:], W[h,:]) + bias[h]
// One block per (b,n). 256 threads = 4 waves; each wave computes 4 heads.
// ---------------------------------------------------------------------------
__global__ __launch_bounds__(256) void logits_kernel(
    const float* __restrict__ x, const float* __restrict__ W,
    const float* __restrict__ bias, float* __restrict__ logits) {
  const int bn   = blockIdx.x;            // b*N + n
  const int tid  = threadIdx.x;
  const int wave = tid >> 6;
  const int lane = tid & 63;

  const f32x4* xrow = (const f32x4*)(x + (size_t)bn * DIM);
  f32x4 xv[4];
#pragma unroll
  for (int k = 0; k < 4; ++k) xv[k] = xrow[lane * 4 + k];

#pragma unroll
  for (int hh = 0; hh < 4; ++hh) {
    const int h = wave * 4 + hh;
    const f32x4* wrow = (const f32x4*)(W + (size_t)h * DIM);
    float s = 0.0f;
#pragma unroll
    for (int k = 0; k < 4; ++k) {
      f32x4 wv = wrow[lane * 4 + k];
      s += wv.x * xv[k].x + wv.y * xv[k].y + wv.z * xv[k].z + wv.w * xv[k].w;
    }
#pragma unroll
    for (int off = 32; off > 0; off >>= 1) s += __shfl_down(s, off, 64);
    if (lane == 0) {
      const int b = bn >> 11;   // / N
      const int n = bn & (N - 1);
      logits[((size_t)(b * HEADS + h)) * N + n] = s + bias[h];
    }
  }
}

// ---------------------------------------------------------------------------
// Kernel 2: fg[bh, :] = cumsum(logsigmoid(logits[bh, :]))
// One block per (b,h) = 32 blocks. 256 threads, 8 elements each (contiguous).
// ---------------------------------------------------------------------------
__device__ __forceinline__ float logsig(float z) {
  return fminf(z, 0.0f) - log1pf(__expf(-fabsf(z)));
}

__global__ __launch_bounds__(256) void cumsum_kernel(
    const float* __restrict__ logits, float* __restrict__ fg) {
  const int bh  = blockIdx.x;
  const int tid = threadIdx.x;
  const float* lp = logits + (size_t)bh * N;
  float*       fp = fg     + (size_t)bh * N;

  f32x4 a = ((const f32x4*)lp)[tid * 2];
  f32x4 c = ((const f32x4*)lp)[tid * 2 + 1];
  float v[8] = {a.x, a.y, a.z, a.w, c.x, c.y, c.z, c.w};

  float run = 0.0f;
#pragma unroll
  for (int i = 0; i < 8; ++i) { v[i] = logsig(v[i]); run += v[i]; v[i] = run; }
  const float total = run;

  const int lane = tid & 63, wv = tid >> 6;
  float sc = total;
#pragma unroll
  for (int off = 1; off < 64; off <<= 1) {
    float t = __shfl_up(sc, off, 64);
    if (lane >= off) sc += t;
  }

  __shared__ float wtot[4];
  if (lane == 63) wtot[wv] = sc;
  __syncthreads();
  float wofs = 0.0f;
  for (int w = 0; w < wv; ++w) wofs += wtot[w];

  const float base = wofs + sc - total;  // exclusive prefix for this thread
  f32x4 o0 = {base + v[0], base + v[1], base + v[2], base + v[3]};
  f32x4 o1 = {base + v[4], base + v[5], base + v[6], base + v[7]};
  ((f32x4*)fp)[tid * 2]     = o0;
  ((f32x4*)fp)[tid * 2 + 1] = o1;
}

// ---------------------------------------------------------------------------
// Kernel 3: out[bh, i, j] = fg[bh, i] - fg[bh, j]
// One block per (bh, 16-row tile). Each thread holds its 2 f32x4 slice of the
// fj row in registers and streams 16 output rows with nontemporal stores.
// Grid: 32 * (2048/16) = 4096 blocks.
// ---------------------------------------------------------------------------
__global__ __launch_bounds__(256) void outer_kernel(
    const float* __restrict__ fg, float* __restrict__ out) {
  const int blk   = blockIdx.x;
  const int tiles = N / ROWS;                 // 128
  const int bh    = blk / tiles;
  const int i0    = (blk % tiles) * ROWS;
  const int tid   = threadIdx.x;

  const float* frow = fg + (size_t)bh * N;
  const f32x4* fj   = (const f32x4*)frow;

  // this thread's slice of the j-row (reused for all 16 output rows)
  f32x4 v0 = fj[tid];
  f32x4 v1 = fj[tid + 256];

  // the 16 row scalars (uniform per block -> scalar loads)
  float fi[ROWS];
#pragma unroll
  for (int r = 0; r < ROWS; ++r) fi[r] = frow[i0 + r];

  f32x4* obase = (f32x4*)(out + ((size_t)bh * N + i0) * N);
#pragma unroll
  for (int r = 0; r < ROWS; ++r) {
    const float f = fi[r];
    f32x4 r0 = {f - v0.x, f - v0.y, f - v0.z, f - v0.w};
    f32x4 r1 = {f - v1.x, f - v1.y, f - v1.z, f - v1.w};
    f32x4* orow = obase + (size_t)r * (N / 4);
    __builtin_nontemporal_store(r0, &orow[tid]);
    __builtin_nontemporal_store(r1, &orow[tid + 256]);
  }
}

extern "C" void kernel_launch(void* const* d_in, const int* in_sizes, int n_in,
                              void* d_out, int out_size, void* d_ws, size_t ws_size,
                              hipStream_t stream) {
  const float* x    = (const float*)d_in[0];   // [B, N, DIM]
  const float* W    = (const float*)d_in[1];   // [HEADS, DIM]
  const float* bias = (const float*)d_in[2];   // [HEADS]
  float* out = (float*)d_out;                  // [B, HEADS, N, N]

  float* logits = (float*)d_ws;                            // B*HEADS*N f32 = 256 KB
  float* fg     = logits + (size_t)B * HEADS * N;          // B*HEADS*N f32 = 256 KB

  logits_kernel<<<B * N, 256, 0, stream>>>(x, W, bias, logits);
  cumsum_kernel<<<B * HEADS, 256, 0, stream>>>(logits, fg);
  outer_kernel<<<B * HEADS * (N / ROWS), 256, 0, stream>>>(fg, out);
}

// Round 4
// 119.523 us; speedup vs baseline: 1.0809x; 1.0809x over previous
//
#include <hip/hip_runtime.h>
#include <hip/hip_bf16.h>

#define DIM   1024
#define HEADS 16
#define B     2
#define N     2048

typedef float f32x4 __attribute__((ext_vector_type(4)));

// ---------------------------------------------------------------------------
// Kernel 1: logits[b,h,n] = dot(x[b,n,:], W[h,:]) + bias[h]
// One block per (b,n). 256 threads = 4 waves; each wave computes 4 heads.
// ---------------------------------------------------------------------------
__global__ __launch_bounds__(256) void logits_kernel(
    const float* __restrict__ x, const float* __restrict__ W,
    const float* __restrict__ bias, float* __restrict__ logits) {
  const int bn   = blockIdx.x;            // b*N + n
  const int tid  = threadIdx.x;
  const int wave = tid >> 6;
  const int lane = tid & 63;

  const f32x4* xrow = (const f32x4*)(x + (size_t)bn * DIM);
  f32x4 xv[4];
#pragma unroll
  for (int k = 0; k < 4; ++k) xv[k] = xrow[lane * 4 + k];

#pragma unroll
  for (int hh = 0; hh < 4; ++hh) {
    const int h = wave * 4 + hh;
    const f32x4* wrow = (const f32x4*)(W + (size_t)h * DIM);
    float s = 0.0f;
#pragma unroll
    for (int k = 0; k < 4; ++k) {
      f32x4 wv = wrow[lane * 4 + k];
      s += wv.x * xv[k].x + wv.y * xv[k].y + wv.z * xv[k].z + wv.w * xv[k].w;
    }
#pragma unroll
    for (int off = 32; off > 0; off >>= 1) s += __shfl_down(s, off, 64);
    if (lane == 0) {
      const int b = bn >> 11;   // / N
      const int n = bn & (N - 1);
      logits[((size_t)(b * HEADS + h)) * N + n] = s + bias[h];
    }
  }
}

// ---------------------------------------------------------------------------
// Kernel 2: fg[bh, :] = cumsum(logsigmoid(logits[bh, :]))
// One block per (b,h) = 32 blocks. 256 threads, 8 elements each (contiguous).
// ---------------------------------------------------------------------------
__device__ __forceinline__ float logsig(float z) {
  return fminf(z, 0.0f) - log1pf(__expf(-fabsf(z)));
}

__global__ __launch_bounds__(256) void cumsum_kernel(
    const float* __restrict__ logits, float* __restrict__ fg) {
  const int bh  = blockIdx.x;
  const int tid = threadIdx.x;
  const float* lp = logits + (size_t)bh * N;
  float*       fp = fg     + (size_t)bh * N;

  f32x4 a = ((const f32x4*)lp)[tid * 2];
  f32x4 c = ((const f32x4*)lp)[tid * 2 + 1];
  float v[8] = {a.x, a.y, a.z, a.w, c.x, c.y, c.z, c.w};

  float run = 0.0f;
#pragma unroll
  for (int i = 0; i < 8; ++i) { v[i] = logsig(v[i]); run += v[i]; v[i] = run; }
  const float total = run;

  const int lane = tid & 63, wv = tid >> 6;
  float sc = total;
#pragma unroll
  for (int off = 1; off < 64; off <<= 1) {
    float t = __shfl_up(sc, off, 64);
    if (lane >= off) sc += t;
  }

  __shared__ float wtot[4];
  if (lane == 63) wtot[wv] = sc;
  __syncthreads();
  float wofs = 0.0f;
  for (int w = 0; w < wv; ++w) wofs += wtot[w];

  const float base = wofs + sc - total;  // exclusive prefix for this thread
  f32x4 o0 = {base + v[0], base + v[1], base + v[2], base + v[3]};
  f32x4 o1 = {base + v[4], base + v[5], base + v[6], base + v[7]};
  ((f32x4*)fp)[tid * 2]     = o0;
  ((f32x4*)fp)[tid * 2 + 1] = o1;
}

// ---------------------------------------------------------------------------
// Kernel 3: out[bh, i, j] = fg[bh, i] - fg[bh, j]
// One block per (bh, i) row (round-2 structure — best so far), but with PLAIN
// stores (no nontemporal): let L2 write-combine and evict full lines.
// ---------------------------------------------------------------------------
__global__ __launch_bounds__(256) void outer_kernel(
    const float* __restrict__ fg, float* __restrict__ out) {
  const int row = blockIdx.x;             // (bh * N + i)
  const int bh  = row >> 11;              // / N
  const int i   = row & (N - 1);
  const float fi = fg[(size_t)bh * N + i];   // block-uniform -> s_load
  const f32x4* fj = (const f32x4*)(fg + (size_t)bh * N);
  f32x4* o = (f32x4*)(out + (size_t)row * N);
  const int tid = threadIdx.x;

  f32x4 v0 = fj[tid];
  f32x4 v1 = fj[tid + 256];
  f32x4 r0 = {fi - v0.x, fi - v0.y, fi - v0.z, fi - v0.w};
  f32x4 r1 = {fi - v1.x, fi - v1.y, fi - v1.z, fi - v1.w};
  o[tid]       = r0;
  o[tid + 256] = r1;
}

extern "C" void kernel_launch(void* const* d_in, const int* in_sizes, int n_in,
                              void* d_out, int out_size, void* d_ws, size_t ws_size,
                              hipStream_t stream) {
  const float* x    = (const float*)d_in[0];   // [B, N, DIM]
  const float* W    = (const float*)d_in[1];   // [HEADS, DIM]
  const float* bias = (const float*)d_in[2];   // [HEADS]
  float* out = (float*)d_out;                  // [B, HEADS, N, N]

  float* logits = (float*)d_ws;                            // B*HEADS*N f32 = 256 KB
  float* fg     = logits + (size_t)B * HEADS * N;          // B*HEADS*N f32 = 256 KB

  logits_kernel<<<B * N, 256, 0, stream>>>(x, W, bias, logits);
  cumsum_kernel<<<B * HEADS, 256, 0, stream>>>(logits, fg);
  outer_kernel<<<B * HEADS * N, 256, 0, stream>>>(fg, out);
}